// Round 2
// baseline (7875.847 us; speedup 1.0000x reference)
//
#include <hip/hip_runtime.h>
#include <stdint.h>
#include <math.h>

// ---------------------------------------------------------------------------
// CosineHammingAttention — bit-faithful HIP port of the JAX reference.
// B=2 H=8 N=4096 D=64, NUM_PROJS=7, BUCKET=256, SAMPLE=800, PM_ITERS=32
// ---------------------------------------------------------------------------

typedef unsigned int u32;

#define PRNG_MODE 0  // 0: partitionable threefry (xor out0^out1)  1: legacy split-iota  2: partitionable word0

namespace {
constexpr int Bc = 2, Hc = 8, BHc = 16;
constexpr int Nc = 4096, Dc = 64, D1c = 65;
constexpr int NPROJc = 7;
constexpr int NBc = 16;      // N / BUCKET
constexpr int Sc = 800;      // SAMPLE
constexpr int PMITERc = 32;
}

__device__ __forceinline__ u32 rotl32(u32 x, u32 d) { return (x << d) | (x >> (32u - d)); }

// Exact JAX threefry2x32 (20 rounds).
__device__ __forceinline__ void threefry2x32(u32 k0, u32 k1, u32 x0, u32 x1, u32& o0, u32& o1) {
  u32 ks2 = k0 ^ k1 ^ 0x1BD11BDAu;
  x0 += k0; x1 += k1;
#define TF_RND(r) { x0 += x1; x1 = rotl32(x1, r); x1 ^= x0; }
  TF_RND(13) TF_RND(15) TF_RND(26) TF_RND(6)
  x0 += k1; x1 += ks2 + 1u;
  TF_RND(17) TF_RND(29) TF_RND(16) TF_RND(24)
  x0 += ks2; x1 += k0 + 2u;
  TF_RND(13) TF_RND(15) TF_RND(26) TF_RND(6)
  x0 += k0; x1 += k1 + 3u;
  TF_RND(17) TF_RND(29) TF_RND(16) TF_RND(24)
  x0 += k1; x1 += ks2 + 4u;
  TF_RND(13) TF_RND(15) TF_RND(26) TF_RND(6)
  x0 += ks2; x1 += k0 + 5u;
#undef TF_RND
  o0 = x0; o1 = x1;
}

// gumbel sample for flat element i of the (800,16,4096) array, key = (0,1234)
__device__ __forceinline__ float gumbel_at(u32 i) {
  u32 o0, o1, bits;
#if PRNG_MODE == 1
  const u32 half = (u32)Sc * (u32)BHc * (u32)Nc / 2u;
  if (i < half) { threefry2x32(0u, 1234u, i, i + half, o0, o1); bits = o0; }
  else          { threefry2x32(0u, 1234u, i - half, i, o0, o1); bits = o1; }
#else
  threefry2x32(0u, 1234u, 0u, i, o0, o1);
#if PRNG_MODE == 0
  bits = o0 ^ o1;
#else
  bits = o0;
#endif
#endif
  u32 fb = (bits >> 9) | 0x3f800000u;
  float u = __uint_as_float(fb) - 1.0f;           // [0,1) on 2^-23 grid
  if (u == 0.0f) u = 1.1754944e-38f;              // max(tiny, u) per jax.random.uniform
  return -logf(-logf(u));
}

// ---- K1: LSH hash codes for q and k ---------------------------------------
__global__ __launch_bounds__(256) void hash_kernel(
    const float* __restrict__ q, const float* __restrict__ k,
    const float* __restrict__ pd, int* __restrict__ hq, int* __restrict__ hk) {
  int tid = blockIdx.x * 256 + threadIdx.x;
  int which = tid / (BHc * Nc);
  int rem = tid % (BHc * Nc);
  int bh = rem / Nc, n = rem % Nc;
  int b = bh / Hc, h = bh % Hc;
  const float* x = which ? k : q;
  const float* row = x + (((size_t)b * Nc + n) * Hc + h) * Dc;   // [B,N,H,D]
  const float* pdr = pd + (size_t)bh * Dc * NPROJc;              // [B,H,D,7]
  double acc[NPROJc];
#pragma unroll
  for (int r = 0; r < NPROJc; r++) acc[r] = 0.0;
  for (int d = 0; d < Dc; d++) {
    double vv = (double)row[d];
    const float* pr = pdr + d * NPROJc;
#pragma unroll
    for (int r = 0; r < NPROJc; r++) acc[r] += vv * (double)pr[r];
  }
  int code = 0;
#pragma unroll
  for (int r = 0; r < NPROJc; r++) code |= (acc[r] > 0.0) ? (1 << r) : 0;
  int hash = code ^ (code >> 1);   // _hamming_perm == binary-reflected Gray code
  (which ? hk : hq)[bh * Nc + n] = hash;
}

// ---- K2: stable counting sort (argsort by hash) ---------------------------
__global__ __launch_bounds__(256) void sort_kernel(
    const int* __restrict__ hq, const int* __restrict__ hk,
    int* __restrict__ qidx, int* __restrict__ kidx) {
  __shared__ int sh[Nc];
  __shared__ int off[128];
  int bh = blockIdx.x;
  const int* hash = blockIdx.y ? hk : hq;
  int* out = blockIdx.y ? kidx : qidx;
  int t = threadIdx.x;
  for (int i = t; i < Nc; i += 256) sh[i] = hash[bh * Nc + i];
  __syncthreads();
  if (t < 128) {
    int c = 0;
    for (int i = 0; i < Nc; i++) c += (sh[i] == t);
    off[t] = c;
  }
  __syncthreads();
  if (t == 0) {
    int run = 0;
    for (int j = 0; j < 128; j++) { int c = off[j]; off[j] = run; run += c; }
  }
  __syncthreads();
  if (t < 128) {
    int o = off[t];
    for (int i = 0; i < Nc; i++)
      if (sh[i] == t) { out[bh * Nc + o] = i; o++; }
  }
}

// ---- K3: sorted-query block id per original query n -----------------------
__global__ __launch_bounds__(256) void qblock_kernel(
    const int* __restrict__ qidx, int* __restrict__ qblk) {
  int tid = blockIdx.x * 256 + threadIdx.x;   // [0, BH*N)
  int bh = tid / Nc, p = tid % Nc;
  int n = qidx[tid];
  qblk[bh * Nc + n] = p >> 8;                 // p / BUCKET
}

// ---- K4: block-sparse attention on sorted buckets -------------------------
__global__ __launch_bounds__(256) void sparse_kernel(
    const float* __restrict__ q, const float* __restrict__ k, const float* __restrict__ v,
    const int* __restrict__ qidx, const int* __restrict__ kidx, float* __restrict__ att) {
  __shared__ float kb[32][Dc];
  __shared__ float wb[32][D1c];
  int bh = blockIdx.x / NBc, g = blockIdx.x % NBc;
  int b = bh / Hc, h = bh % Hc;
  int t = threadIdx.x;
  int nq = qidx[bh * Nc + g * 256 + t];
  const float* qrow = q + (((size_t)b * Nc + nq) * Hc + h) * Dc;
  float qreg[Dc];
#pragma unroll
  for (int d = 0; d < Dc; d++) qreg[d] = qrow[d];
  float acc[D1c];
#pragma unroll
  for (int p = 0; p < D1c; p++) acc[p] = 0.f;
  for (int c = 0; c < 8; c++) {
    for (int e = t; e < 32 * Dc; e += 256) {
      int r = e / Dc, d = e % Dc;
      int m = kidx[bh * Nc + g * 256 + c * 32 + r];
      kb[r][d] = k[(((size_t)b * Nc + m) * Hc + h) * Dc + d];
    }
    for (int e = t; e < 32 * D1c; e += 256) {
      int r = e / D1c, p = e % D1c;
      int m = kidx[bh * Nc + g * 256 + c * 32 + r];
      wb[r][p] = (p < Dc) ? v[(((size_t)b * Nc + m) * Hc + h) * Dc + p] : 1.0f;
    }
    __syncthreads();
    for (int j = 0; j < 32; j++) {
      float s0 = 0, s1 = 0, s2 = 0, s3 = 0;
#pragma unroll
      for (int d = 0; d < Dc; d += 4) {
        s0 += qreg[d] * kb[j][d];
        s1 += qreg[d + 1] * kb[j][d + 1];
        s2 += qreg[d + 2] * kb[j][d + 2];
        s3 += qreg[d + 3] * kb[j][d + 3];
      }
      float e_ = expf((s0 + s1) + (s2 + s3));
#pragma unroll
      for (int p = 0; p < D1c; p++) acc[p] += e_ * wb[j][p];
    }
    __syncthreads();
  }
  float* arow = att + ((size_t)bh * Nc + nq) * D1c;   // scatter back to original order
#pragma unroll
  for (int p = 0; p < D1c; p++) arow[p] = acc[p];
}

// ---- K5: Gram = v_aug^T v_aug (order-independent of sort) -----------------
__global__ __launch_bounds__(256) void gram_kernel(
    const float* __restrict__ v, double* __restrict__ gram) {
  __shared__ float ch[64][D1c];
  int bh = blockIdx.x, b = bh / Hc, h = bh % Hc;
  int t = threadIdx.x;
  double acc[17];
#pragma unroll
  for (int i = 0; i < 17; i++) acc[i] = 0.0;
  for (int c = 0; c < Nc / 64; c++) {
    for (int e = t; e < 64 * D1c; e += 256) {
      int r = e / D1c, p = e % D1c;
      int n = c * 64 + r;
      ch[r][p] = (p < Dc) ? v[(((size_t)b * Nc + n) * Hc + h) * Dc + p] : 1.0f;
    }
    __syncthreads();
#pragma unroll
    for (int i = 0; i < 17; i++) {
      int pi = t + 256 * i;
      if (pi < D1c * D1c) {
        int tt = pi / D1c, uu = pi % D1c;
        double a = 0.0;
        for (int r = 0; r < 64; r++) a += (double)ch[r][tt] * (double)ch[r][uu];
        acc[i] += a;
      }
    }
    __syncthreads();
  }
#pragma unroll
  for (int i = 0; i < 17; i++) {
    int pi = t + 256 * i;
    if (pi < D1c * D1c) gram[(size_t)bh * D1c * D1c + pi] = acc[i];
  }
}

// ---- K6: power method for spectral norm -----------------------------------
__global__ __launch_bounds__(128) void power_kernel(
    const double* __restrict__ gram, const float* __restrict__ pm, double* __restrict__ sigma) {
  __shared__ double G[D1c * D1c];
  __shared__ double x[D1c], y[D1c];
  __shared__ double nrm;
  int bh = blockIdx.x, t = threadIdx.x;
  for (int e = t; e < D1c * D1c; e += 128) G[e] = gram[(size_t)bh * D1c * D1c + e];
  if (t < D1c) x[t] = (double)pm[bh * D1c + t];
  __syncthreads();
  if (t == 0) {
    double s = 0; for (int i = 0; i < D1c; i++) s += x[i] * x[i];
    nrm = sqrt(s);
  }
  __syncthreads();
  if (t < D1c) x[t] /= nrm;
  for (int it = 0; it < PMITERc; it++) {
    __syncthreads();
    if (t < D1c) {
      double s = 0;
      for (int u = 0; u < D1c; u++) s += G[t * D1c + u] * x[u];
      y[t] = s;
    }
    __syncthreads();
    if (t == 0) {
      double s = 0; for (int i = 0; i < D1c; i++) s += y[i] * y[i];
      nrm = sqrt(s);
    }
    __syncthreads();
    if (t < D1c) x[t] = y[t] / nrm;
  }
  __syncthreads();
  if (t == 0) sigma[bh] = nrm;
}

// ---- K7: sampling distribution P (sorted-key order) + log P ---------------
__global__ __launch_bounds__(256) void p_kernel(
    const float* __restrict__ v, const int* __restrict__ kidx,
    const double* __restrict__ sigma, float* __restrict__ P, float* __restrict__ logP) {
  __shared__ double buf[Nc];
  __shared__ double red[256];
  int bh = blockIdx.x, b = bh / Hc, h = bh % Hc;
  int t = threadIdx.x;
  double sg = sigma[bh];
  double part = 0.0;
  for (int n = t; n < Nc; n += 256) {
    int m = kidx[bh * Nc + n];
    const float* vr = v + (((size_t)b * Nc + m) * Hc + h) * Dc;
    double ss = 1.0;  // the appended 1.0 component of v_aug
    for (int d = 0; d < Dc; d++) { double vv = vr[d]; ss += vv * vv; }
    double Pd = sqrt(ss) / sg + (1.0 / (double)Nc);
    buf[n] = Pd;
    part += Pd;
  }
  red[t] = part;
  __syncthreads();
  for (int w = 128; w > 0; w >>= 1) {
    if (t < w) red[t] += red[t + w];
    __syncthreads();
  }
  double tot = red[0];
  for (int n = t; n < Nc; n += 256) {
    float Pf = (float)(buf[n] / tot);
    P[bh * Nc + n] = Pf;
    logP[bh * Nc + n] = logf(Pf);
  }
}

// ---- K8: categorical sampling = argmax(gumbel + logP) ---------------------
__global__ __launch_bounds__(256) void sample_kernel(
    const float* __restrict__ logP, int* __restrict__ idxs) {
  __shared__ float sv[256];
  __shared__ int si[256];
  int blk = blockIdx.x;           // bh*S + s
  int bh = blk / Sc, s = blk % Sc;
  int t = threadIdx.x;
  float best = -3.4e38f; int besti = Nc;
  const float* lp = logP + bh * Nc;
  u32 base = ((u32)(s * BHc + bh)) * (u32)Nc;  // flat index into (800,16,4096)
  for (int n = t; n < Nc; n += 256) {
    float val = gumbel_at(base + (u32)n) + lp[n];
    if (val > best || (val == best && n < besti)) { best = val; besti = n; }
  }
  sv[t] = best; si[t] = besti;
  __syncthreads();
  for (int w = 128; w > 0; w >>= 1) {
    if (t < w) {
      float v2 = sv[t + w]; int i2 = si[t + w];
      if (v2 > sv[t] || (v2 == sv[t] && i2 < si[t])) { sv[t] = v2; si[t] = i2; }
    }
    __syncthreads();
  }
  if (t == 0) idxs[blk] = si[0];
}

// ---- K9: gather sampled K rows, sig*V_aug rows, sample block ids ----------
__global__ __launch_bounds__(128) void gather_kernel(
    const float* __restrict__ key, const float* __restrict__ value,
    const int* __restrict__ kidx, const float* __restrict__ P, const int* __restrict__ idxs,
    float* __restrict__ Kpi, float* __restrict__ sigV, int* __restrict__ sblk) {
  int blk = blockIdx.x;           // bh*S + s
  int bh = blk / Sc;
  int b = bh / Hc, h = bh % Hc;
  int t = threadIdx.x;
  int m = idxs[blk];
  int src = kidx[bh * Nc + m];
  float Pv = P[bh * Nc + m];
  float sg = 1.0f / (Pv * (float)Sc);
  const float* kr = key + (((size_t)b * Nc + src) * Hc + h) * Dc;
  const float* vr = value + (((size_t)b * Nc + src) * Hc + h) * Dc;
  if (t < Dc) Kpi[(size_t)blk * Dc + t] = kr[t];
  if (t < D1c) sigV[(size_t)blk * D1c + t] = sg * ((t < Dc) ? vr[t] : 1.0f);
  if (t == 0) sblk[blk] = m >> 8;
}

// ---- K10: residual attention + combine + final divide ---------------------
__global__ __launch_bounds__(256) void residual_kernel(
    const float* __restrict__ q,
    const float* __restrict__ Kpi, const float* __restrict__ sigV, const int* __restrict__ sblk,
    const int* __restrict__ qblk, const float* __restrict__ att, float* __restrict__ out) {
  __shared__ float kl[32][Dc];
  __shared__ float wl[32][D1c];
  __shared__ int bl[32];
  int rid = blockIdx.x * 256 + threadIdx.x;   // 256 consecutive rows share one bh
  int bh = rid / Nc, n = rid % Nc;
  int b = bh / Hc, h = bh % Hc;
  int t = threadIdx.x;
  const float* qrow = q + (((size_t)b * Nc + n) * Hc + h) * Dc;
  float qreg[Dc];
#pragma unroll
  for (int d = 0; d < Dc; d++) qreg[d] = qrow[d];
  int myblk = qblk[bh * Nc + n];
  float acc[D1c];
#pragma unroll
  for (int p = 0; p < D1c; p++) acc[p] = 0.f;
  for (int c = 0; c < Sc / 32; c++) {
    for (int e = t; e < 32 * Dc; e += 256) {
      int r = e / Dc, d = e % Dc;
      kl[r][d] = Kpi[((size_t)bh * Sc + c * 32 + r) * Dc + d];
    }
    for (int e = t; e < 32 * D1c; e += 256) {
      int r = e / D1c, p = e % D1c;
      wl[r][p] = sigV[((size_t)bh * Sc + c * 32 + r) * D1c + p];
    }
    if (t < 32) bl[t] = sblk[bh * Sc + c * 32 + t];
    __syncthreads();
    for (int j = 0; j < 32; j++) {
      float s0 = 0, s1 = 0, s2 = 0, s3 = 0;
#pragma unroll
      for (int d = 0; d < Dc; d += 4) {
        s0 += qreg[d] * kl[j][d];
        s1 += qreg[d + 1] * kl[j][d + 1];
        s2 += qreg[d + 2] * kl[j][d + 2];
        s3 += qreg[d + 3] * kl[j][d + 3];
      }
      float e_ = expf((s0 + s1) + (s2 + s3));
      float w = (bl[j] == myblk) ? 0.0f : e_;   // mask: sample in query's own block
#pragma unroll
      for (int p = 0; p < D1c; p++) acc[p] += w * wl[j][p];
    }
    __syncthreads();
  }
  const float* arow = att + ((size_t)bh * Nc + n) * D1c;
  float denom = arow[Dc] + acc[Dc];
  float* orow = out + ((size_t)bh * Nc + n) * Dc;
#pragma unroll
  for (int d = 0; d < Dc; d++) orow[d] = (arow[d] + acc[d]) / denom;
}

// ---------------------------------------------------------------------------
extern "C" void kernel_launch(void* const* d_in, const int* in_sizes, int n_in,
                              void* d_out, int out_size, void* d_ws, size_t ws_size,
                              hipStream_t stream) {
  const float* q  = (const float*)d_in[0];
  const float* k  = (const float*)d_in[1];
  const float* v  = (const float*)d_in[2];
  const float* pd = (const float*)d_in[3];
  const float* pm = (const float*)d_in[4];
  float* out = (float*)d_out;

  char* w = (char*)d_ws;
  size_t off = 0;
  auto take = [&](size_t nbytes) -> void* {
    void* p = w + off;
    off += (nbytes + 255) & ~(size_t)255;
    return p;
  };
  double* gram = (double*)take((size_t)BHc * D1c * D1c * sizeof(double));
  double* sigm = (double*)take((size_t)BHc * sizeof(double));
  int* hq   = (int*)take((size_t)BHc * Nc * 4);
  int* hk   = (int*)take((size_t)BHc * Nc * 4);
  int* qidx = (int*)take((size_t)BHc * Nc * 4);
  int* kidx = (int*)take((size_t)BHc * Nc * 4);
  int* qblk = (int*)take((size_t)BHc * Nc * 4);
  float* P    = (float*)take((size_t)BHc * Nc * 4);
  float* logP = (float*)take((size_t)BHc * Nc * 4);
  int* idxs = (int*)take((size_t)BHc * Sc * 4);
  int* sblk = (int*)take((size_t)BHc * Sc * 4);
  float* Kpi  = (float*)take((size_t)BHc * Sc * Dc * 4);
  float* sigV = (float*)take((size_t)BHc * Sc * D1c * 4);
  float* att  = (float*)take((size_t)BHc * Nc * D1c * 4);
  (void)ws_size; (void)in_sizes; (void)n_in; (void)out_size;

  hash_kernel<<<2 * BHc * Nc / 256, 256, 0, stream>>>(q, k, pd, hq, hk);
  sort_kernel<<<dim3(BHc, 2), 256, 0, stream>>>(hq, hk, qidx, kidx);
  qblock_kernel<<<BHc * Nc / 256, 256, 0, stream>>>(qidx, qblk);
  sparse_kernel<<<BHc * NBc, 256, 0, stream>>>(q, k, v, qidx, kidx, att);
  gram_kernel<<<BHc, 256, 0, stream>>>(v, gram);
  power_kernel<<<BHc, 128, 0, stream>>>(gram, pm, sigm);
  p_kernel<<<BHc, 256, 0, stream>>>(v, kidx, sigm, P, logP);
  sample_kernel<<<BHc * Sc, 256, 0, stream>>>(logP, idxs);
  gather_kernel<<<BHc * Sc, 128, 0, stream>>>(k, v, kidx, P, idxs, Kpi, sigV, sblk);
  residual_kernel<<<BHc * Nc / 256, 256, 0, stream>>>(q, Kpi, sigV, sblk, qblk, att, out);
}

// Round 3
// 2183.670 us; speedup vs baseline: 3.6067x; 3.6067x over previous
//
#include <hip/hip_runtime.h>
#include <stdint.h>
#include <math.h>

// ---------------------------------------------------------------------------
// CosineHammingAttention — bit-faithful HIP port of the JAX reference.
// B=2 H=8 N=4096 D=64, NUM_PROJS=7, BUCKET=256, SAMPLE=800, PM_ITERS=32
// R2: parallelize Gram (16 -> 512 blocks, partial+reduce), alias partials
//     onto att buffer (sparse_kernel moved after gram_reduce).
// ---------------------------------------------------------------------------

typedef unsigned int u32;

#define PRNG_MODE 0  // 0: partitionable threefry (xor out0^out1)  1: legacy split-iota

namespace {
constexpr int Bc = 2, Hc = 8, BHc = 16;
constexpr int Nc = 4096, Dc = 64, D1c = 65;
constexpr int NPROJc = 7;
constexpr int NBc = 16;      // N / BUCKET
constexpr int Sc = 800;      // SAMPLE
constexpr int PMITERc = 32;
constexpr int GCH = 128;             // Gram rows per chunk
constexpr int NCHUNK = Nc / GCH;     // 32
}

__device__ __forceinline__ u32 rotl32(u32 x, u32 d) { return (x << d) | (x >> (32u - d)); }

// Exact JAX threefry2x32 (20 rounds).
__device__ __forceinline__ void threefry2x32(u32 k0, u32 k1, u32 x0, u32 x1, u32& o0, u32& o1) {
  u32 ks2 = k0 ^ k1 ^ 0x1BD11BDAu;
  x0 += k0; x1 += k1;
#define TF_RND(r) { x0 += x1; x1 = rotl32(x1, r); x1 ^= x0; }
  TF_RND(13) TF_RND(15) TF_RND(26) TF_RND(6)
  x0 += k1; x1 += ks2 + 1u;
  TF_RND(17) TF_RND(29) TF_RND(16) TF_RND(24)
  x0 += ks2; x1 += k0 + 2u;
  TF_RND(13) TF_RND(15) TF_RND(26) TF_RND(6)
  x0 += k0; x1 += k1 + 3u;
  TF_RND(17) TF_RND(29) TF_RND(16) TF_RND(24)
  x0 += k1; x1 += ks2 + 4u;
  TF_RND(13) TF_RND(15) TF_RND(26) TF_RND(6)
  x0 += ks2; x1 += k0 + 5u;
#undef TF_RND
  o0 = x0; o1 = x1;
}

// gumbel sample for flat element i of the (800,16,4096) array, key = (0,1234)
__device__ __forceinline__ float gumbel_at(u32 i) {
  u32 o0, o1, bits;
#if PRNG_MODE == 1
  const u32 half = (u32)Sc * (u32)BHc * (u32)Nc / 2u;
  if (i < half) { threefry2x32(0u, 1234u, i, i + half, o0, o1); bits = o0; }
  else          { threefry2x32(0u, 1234u, i - half, i, o0, o1); bits = o1; }
#else
  threefry2x32(0u, 1234u, 0u, i, o0, o1);
  bits = o0 ^ o1;
#endif
  u32 fb = (bits >> 9) | 0x3f800000u;
  float u = __uint_as_float(fb) - 1.0f;           // [0,1) on 2^-23 grid
  if (u == 0.0f) u = 1.1754944e-38f;              // max(tiny, u) per jax.random.uniform
  return -logf(-logf(u));
}

// ---- K1: LSH hash codes for q and k ---------------------------------------
__global__ __launch_bounds__(256) void hash_kernel(
    const float* __restrict__ q, const float* __restrict__ k,
    const float* __restrict__ pd, int* __restrict__ hq, int* __restrict__ hk) {
  int tid = blockIdx.x * 256 + threadIdx.x;
  int which = tid / (BHc * Nc);
  int rem = tid % (BHc * Nc);
  int bh = rem / Nc, n = rem % Nc;
  int b = bh / Hc, h = bh % Hc;
  const float* x = which ? k : q;
  const float* row = x + (((size_t)b * Nc + n) * Hc + h) * Dc;   // [B,N,H,D]
  const float* pdr = pd + (size_t)bh * Dc * NPROJc;              // [B,H,D,7]
  double acc[NPROJc];
#pragma unroll
  for (int r = 0; r < NPROJc; r++) acc[r] = 0.0;
  for (int d = 0; d < Dc; d++) {
    double vv = (double)row[d];
    const float* pr = pdr + d * NPROJc;
#pragma unroll
    for (int r = 0; r < NPROJc; r++) acc[r] += vv * (double)pr[r];
  }
  int code = 0;
#pragma unroll
  for (int r = 0; r < NPROJc; r++) code |= (acc[r] > 0.0) ? (1 << r) : 0;
  int hash = code ^ (code >> 1);   // _hamming_perm == binary-reflected Gray code
  (which ? hk : hq)[bh * Nc + n] = hash;
}

// ---- K2: stable counting sort (argsort by hash) ---------------------------
__global__ __launch_bounds__(256) void sort_kernel(
    const int* __restrict__ hq, const int* __restrict__ hk,
    int* __restrict__ qidx, int* __restrict__ kidx) {
  __shared__ int sh[Nc];
  __shared__ int off[128];
  int bh = blockIdx.x;
  const int* hash = blockIdx.y ? hk : hq;
  int* out = blockIdx.y ? kidx : qidx;
  int t = threadIdx.x;
  for (int i = t; i < Nc; i += 256) sh[i] = hash[bh * Nc + i];
  __syncthreads();
  if (t < 128) {
    int c = 0;
    for (int i = 0; i < Nc; i++) c += (sh[i] == t);
    off[t] = c;
  }
  __syncthreads();
  if (t == 0) {
    int run = 0;
    for (int j = 0; j < 128; j++) { int c = off[j]; off[j] = run; run += c; }
  }
  __syncthreads();
  if (t < 128) {
    int o = off[t];
    for (int i = 0; i < Nc; i++)
      if (sh[i] == t) { out[bh * Nc + o] = i; o++; }
  }
}

// ---- K3: sorted-query block id per original query n -----------------------
__global__ __launch_bounds__(256) void qblock_kernel(
    const int* __restrict__ qidx, int* __restrict__ qblk) {
  int tid = blockIdx.x * 256 + threadIdx.x;   // [0, BH*N)
  int bh = tid / Nc, p = tid % Nc;
  int n = qidx[tid];
  qblk[bh * Nc + n] = p >> 8;                 // p / BUCKET
}

// ---- K4: block-sparse attention on sorted buckets -------------------------
__global__ __launch_bounds__(256) void sparse_kernel(
    const float* __restrict__ q, const float* __restrict__ k, const float* __restrict__ v,
    const int* __restrict__ qidx, const int* __restrict__ kidx, float* __restrict__ att) {
  __shared__ float kb[32][Dc];
  __shared__ float wb[32][D1c];
  int bh = blockIdx.x / NBc, g = blockIdx.x % NBc;
  int b = bh / Hc, h = bh % Hc;
  int t = threadIdx.x;
  int nq = qidx[bh * Nc + g * 256 + t];
  const float* qrow = q + (((size_t)b * Nc + nq) * Hc + h) * Dc;
  float qreg[Dc];
#pragma unroll
  for (int d = 0; d < Dc; d++) qreg[d] = qrow[d];
  float acc[D1c];
#pragma unroll
  for (int p = 0; p < D1c; p++) acc[p] = 0.f;
  for (int c = 0; c < 8; c++) {
    for (int e = t; e < 32 * Dc; e += 256) {
      int r = e / Dc, d = e % Dc;
      int m = kidx[bh * Nc + g * 256 + c * 32 + r];
      kb[r][d] = k[(((size_t)b * Nc + m) * Hc + h) * Dc + d];
    }
    for (int e = t; e < 32 * D1c; e += 256) {
      int r = e / D1c, p = e % D1c;
      int m = kidx[bh * Nc + g * 256 + c * 32 + r];
      wb[r][p] = (p < Dc) ? v[(((size_t)b * Nc + m) * Hc + h) * Dc + p] : 1.0f;
    }
    __syncthreads();
    for (int j = 0; j < 32; j++) {
      float s0 = 0, s1 = 0, s2 = 0, s3 = 0;
#pragma unroll
      for (int d = 0; d < Dc; d += 4) {
        s0 += qreg[d] * kb[j][d];
        s1 += qreg[d + 1] * kb[j][d + 1];
        s2 += qreg[d + 2] * kb[j][d + 2];
        s3 += qreg[d + 3] * kb[j][d + 3];
      }
      float e_ = expf((s0 + s1) + (s2 + s3));
#pragma unroll
      for (int p = 0; p < D1c; p++) acc[p] += e_ * wb[j][p];
    }
    __syncthreads();
  }
  float* arow = att + ((size_t)bh * Nc + nq) * D1c;   // scatter back to original order
#pragma unroll
  for (int p = 0; p < D1c; p++) arow[p] = acc[p];
}

// ---- K5a: partial Gram over 128-row chunks (grid = BH * 32) ---------------
__global__ __launch_bounds__(256) void gram_partial_kernel(
    const float* __restrict__ v, double* __restrict__ part) {
  __shared__ float ch[GCH][D1c];
  int bh = blockIdx.x / NCHUNK, c = blockIdx.x % NCHUNK;
  int b = bh / Hc, h = bh % Hc;
  int t = threadIdx.x;
  for (int e = t; e < GCH * D1c; e += 256) {
    int r = e / D1c, p = e % D1c;
    int n = c * GCH + r;
    ch[r][p] = (p < Dc) ? v[(((size_t)b * Nc + n) * Hc + h) * Dc + p] : 1.0f;
  }
  __syncthreads();
  for (int pi = t; pi < D1c * D1c; pi += 256) {
    int tt = pi / D1c, uu = pi % D1c;
    double a = 0.0;
    for (int r = 0; r < GCH; r++) a += (double)ch[r][tt] * (double)ch[r][uu];
    part[((size_t)bh * NCHUNK + c) * (D1c * D1c) + pi] = a;
  }
}

// ---- K5b: reduce chunk partials (fixed order -> deterministic) ------------
__global__ __launch_bounds__(256) void gram_reduce_kernel(
    const double* __restrict__ part, double* __restrict__ gram) {
  int idx = blockIdx.x * 256 + threadIdx.x;   // over BH * 4225
  if (idx >= BHc * D1c * D1c) return;
  int bh = idx / (D1c * D1c), pi = idx % (D1c * D1c);
  double s = 0.0;
  for (int c = 0; c < NCHUNK; c++)
    s += part[((size_t)bh * NCHUNK + c) * (D1c * D1c) + pi];
  gram[(size_t)bh * (D1c * D1c) + pi] = s;
}

// ---- K6: power method for spectral norm -----------------------------------
__global__ __launch_bounds__(128) void power_kernel(
    const double* __restrict__ gram, const float* __restrict__ pm, double* __restrict__ sigma) {
  __shared__ double G[D1c * D1c];
  __shared__ double x[D1c], y[D1c];
  __shared__ double nrm;
  int bh = blockIdx.x, t = threadIdx.x;
  for (int e = t; e < D1c * D1c; e += 128) G[e] = gram[(size_t)bh * D1c * D1c + e];
  if (t < D1c) x[t] = (double)pm[bh * D1c + t];
  __syncthreads();
  if (t == 0) {
    double s = 0; for (int i = 0; i < D1c; i++) s += x[i] * x[i];
    nrm = sqrt(s);
  }
  __syncthreads();
  if (t < D1c) x[t] /= nrm;
  for (int it = 0; it < PMITERc; it++) {
    __syncthreads();
    if (t < D1c) {
      double s = 0;
      for (int u = 0; u < D1c; u++) s += G[t * D1c + u] * x[u];
      y[t] = s;
    }
    __syncthreads();
    if (t == 0) {
      double s = 0; for (int i = 0; i < D1c; i++) s += y[i] * y[i];
      nrm = sqrt(s);
    }
    __syncthreads();
    if (t < D1c) x[t] = y[t] / nrm;
  }
  __syncthreads();
  if (t == 0) sigma[bh] = nrm;
}

// ---- K7: sampling distribution P (sorted-key order) + log P ---------------
__global__ __launch_bounds__(256) void p_kernel(
    const float* __restrict__ v, const int* __restrict__ kidx,
    const double* __restrict__ sigma, float* __restrict__ P, float* __restrict__ logP) {
  __shared__ double buf[Nc];
  __shared__ double red[256];
  int bh = blockIdx.x, b = bh / Hc, h = bh % Hc;
  int t = threadIdx.x;
  double sg = sigma[bh];
  double part = 0.0;
  for (int n = t; n < Nc; n += 256) {
    int m = kidx[bh * Nc + n];
    const float* vr = v + (((size_t)b * Nc + m) * Hc + h) * Dc;
    double ss = 1.0;  // the appended 1.0 component of v_aug
    for (int d = 0; d < Dc; d++) { double vv = vr[d]; ss += vv * vv; }
    double Pd = sqrt(ss) / sg + (1.0 / (double)Nc);
    buf[n] = Pd;
    part += Pd;
  }
  red[t] = part;
  __syncthreads();
  for (int w = 128; w > 0; w >>= 1) {
    if (t < w) red[t] += red[t + w];
    __syncthreads();
  }
  double tot = red[0];
  for (int n = t; n < Nc; n += 256) {
    float Pf = (float)(buf[n] / tot);
    P[bh * Nc + n] = Pf;
    logP[bh * Nc + n] = logf(Pf);
  }
}

// ---- K8: categorical sampling = argmax(gumbel + logP) ---------------------
__global__ __launch_bounds__(256) void sample_kernel(
    const float* __restrict__ logP, int* __restrict__ idxs) {
  __shared__ float sv[256];
  __shared__ int si[256];
  int blk = blockIdx.x;           // bh*S + s
  int bh = blk / Sc, s = blk % Sc;
  int t = threadIdx.x;
  float best = -3.4e38f; int besti = Nc;
  const float* lp = logP + bh * Nc;
  u32 base = ((u32)(s * BHc + bh)) * (u32)Nc;  // flat index into (800,16,4096)
  for (int n = t; n < Nc; n += 256) {
    float val = gumbel_at(base + (u32)n) + lp[n];
    if (val > best || (val == best && n < besti)) { best = val; besti = n; }
  }
  sv[t] = best; si[t] = besti;
  __syncthreads();
  for (int w = 128; w > 0; w >>= 1) {
    if (t < w) {
      float v2 = sv[t + w]; int i2 = si[t + w];
      if (v2 > sv[t] || (v2 == sv[t] && i2 < si[t])) { sv[t] = v2; si[t] = i2; }
    }
    __syncthreads();
  }
  if (t == 0) idxs[blk] = si[0];
}

// ---- K9: gather sampled K rows, sig*V_aug rows, sample block ids ----------
__global__ __launch_bounds__(128) void gather_kernel(
    const float* __restrict__ key, const float* __restrict__ value,
    const int* __restrict__ kidx, const float* __restrict__ P, const int* __restrict__ idxs,
    float* __restrict__ Kpi, float* __restrict__ sigV, int* __restrict__ sblk) {
  int blk = blockIdx.x;           // bh*S + s
  int bh = blk / Sc;
  int b = bh / Hc, h = bh % Hc;
  int t = threadIdx.x;
  int m = idxs[blk];
  int src = kidx[bh * Nc + m];
  float Pv = P[bh * Nc + m];
  float sg = 1.0f / (Pv * (float)Sc);
  const float* kr = key + (((size_t)b * Nc + src) * Hc + h) * Dc;
  const float* vr = value + (((size_t)b * Nc + src) * Hc + h) * Dc;
  if (t < Dc) Kpi[(size_t)blk * Dc + t] = kr[t];
  if (t < D1c) sigV[(size_t)blk * D1c + t] = sg * ((t < Dc) ? vr[t] : 1.0f);
  if (t == 0) sblk[blk] = m >> 8;
}

// ---- K10: residual attention + combine + final divide ---------------------
__global__ __launch_bounds__(256) void residual_kernel(
    const float* __restrict__ q,
    const float* __restrict__ Kpi, const float* __restrict__ sigV, const int* __restrict__ sblk,
    const int* __restrict__ qblk, const float* __restrict__ att, float* __restrict__ out) {
  __shared__ float kl[32][Dc];
  __shared__ float wl[32][D1c];
  __shared__ int bl[32];
  int rid = blockIdx.x * 256 + threadIdx.x;   // 256 consecutive rows share one bh
  int bh = rid / Nc, n = rid % Nc;
  int b = bh / Hc, h = bh % Hc;
  int t = threadIdx.x;
  const float* qrow = q + (((size_t)b * Nc + n) * Hc + h) * Dc;
  float qreg[Dc];
#pragma unroll
  for (int d = 0; d < Dc; d++) qreg[d] = qrow[d];
  int myblk = qblk[bh * Nc + n];
  float acc[D1c];
#pragma unroll
  for (int p = 0; p < D1c; p++) acc[p] = 0.f;
  for (int c = 0; c < Sc / 32; c++) {
    for (int e = t; e < 32 * Dc; e += 256) {
      int r = e / Dc, d = e % Dc;
      kl[r][d] = Kpi[((size_t)bh * Sc + c * 32 + r) * Dc + d];
    }
    for (int e = t; e < 32 * D1c; e += 256) {
      int r = e / D1c, p = e % D1c;
      wl[r][p] = sigV[((size_t)bh * Sc + c * 32 + r) * D1c + p];
    }
    if (t < 32) bl[t] = sblk[bh * Sc + c * 32 + t];
    __syncthreads();
    for (int j = 0; j < 32; j++) {
      float s0 = 0, s1 = 0, s2 = 0, s3 = 0;
#pragma unroll
      for (int d = 0; d < Dc; d += 4) {
        s0 += qreg[d] * kl[j][d];
        s1 += qreg[d + 1] * kl[j][d + 1];
        s2 += qreg[d + 2] * kl[j][d + 2];
        s3 += qreg[d + 3] * kl[j][d + 3];
      }
      float e_ = expf((s0 + s1) + (s2 + s3));
      float w = (bl[j] == myblk) ? 0.0f : e_;   // mask: sample in query's own block
#pragma unroll
      for (int p = 0; p < D1c; p++) acc[p] += w * wl[j][p];
    }
    __syncthreads();
  }
  const float* arow = att + ((size_t)bh * Nc + n) * D1c;
  float denom = arow[Dc] + acc[Dc];
  float* orow = out + ((size_t)bh * Nc + n) * Dc;
#pragma unroll
  for (int d = 0; d < Dc; d++) orow[d] = (arow[d] + acc[d]) / denom;
}

// ---------------------------------------------------------------------------
extern "C" void kernel_launch(void* const* d_in, const int* in_sizes, int n_in,
                              void* d_out, int out_size, void* d_ws, size_t ws_size,
                              hipStream_t stream) {
  const float* q  = (const float*)d_in[0];
  const float* k  = (const float*)d_in[1];
  const float* v  = (const float*)d_in[2];
  const float* pd = (const float*)d_in[3];
  const float* pm = (const float*)d_in[4];
  float* out = (float*)d_out;

  char* w = (char*)d_ws;
  size_t off = 0;
  auto take = [&](size_t nbytes) -> void* {
    void* p = w + off;
    off += (nbytes + 255) & ~(size_t)255;
    return p;
  };
  double* gram = (double*)take((size_t)BHc * D1c * D1c * sizeof(double));
  double* sigm = (double*)take((size_t)BHc * sizeof(double));
  int* hq   = (int*)take((size_t)BHc * Nc * 4);
  int* hk   = (int*)take((size_t)BHc * Nc * 4);
  int* qidx = (int*)take((size_t)BHc * Nc * 4);
  int* kidx = (int*)take((size_t)BHc * Nc * 4);
  int* qblk = (int*)take((size_t)BHc * Nc * 4);
  float* P    = (float*)take((size_t)BHc * Nc * 4);
  float* logP = (float*)take((size_t)BHc * Nc * 4);
  int* idxs = (int*)take((size_t)BHc * Sc * 4);
  int* sblk = (int*)take((size_t)BHc * Sc * 4);
  float* Kpi  = (float*)take((size_t)BHc * Sc * Dc * 4);
  float* sigV = (float*)take((size_t)BHc * Sc * D1c * 4);
  // union region: Gram chunk partials (used first), then att (written after
  // gram_reduce has consumed the partials — stream order guarantees this).
  size_t partBytes = (size_t)BHc * NCHUNK * D1c * D1c * sizeof(double);
  size_t attBytes  = (size_t)BHc * Nc * D1c * 4;
  void* uni = take(partBytes > attBytes ? partBytes : attBytes);
  double* part = (double*)uni;
  float*  att  = (float*)uni;
  (void)ws_size; (void)in_sizes; (void)n_in; (void)out_size;

  hash_kernel<<<2 * BHc * Nc / 256, 256, 0, stream>>>(q, k, pd, hq, hk);
  sort_kernel<<<dim3(BHc, 2), 256, 0, stream>>>(hq, hk, qidx, kidx);
  qblock_kernel<<<BHc * Nc / 256, 256, 0, stream>>>(qidx, qblk);
  gram_partial_kernel<<<BHc * NCHUNK, 256, 0, stream>>>(v, part);
  gram_reduce_kernel<<<(BHc * D1c * D1c + 255) / 256, 256, 0, stream>>>(part, gram);
  power_kernel<<<BHc, 128, 0, stream>>>(gram, pm, sigm);
  p_kernel<<<BHc, 256, 0, stream>>>(v, kidx, sigm, P, logP);
  sample_kernel<<<BHc * Sc, 256, 0, stream>>>(logP, idxs);
  gather_kernel<<<BHc * Sc, 128, 0, stream>>>(k, v, kidx, P, idxs, Kpi, sigV, sblk);
  sparse_kernel<<<BHc * NBc, 256, 0, stream>>>(q, k, v, qidx, kidx, att);   // writes att (over part)
  residual_kernel<<<BHc * Nc / 256, 256, 0, stream>>>(q, Kpi, sigV, sblk, qblk, att, out);
}

// Round 5
// 1215.554 us; speedup vs baseline: 6.4792x; 1.7964x over previous
//
#include <hip/hip_runtime.h>
#include <stdint.h>
#include <math.h>

// ---------------------------------------------------------------------------
// CosineHammingAttention — bit-faithful HIP port of the JAX reference.
// B=2 H=8 N=4096 D=64, NUM_PROJS=7, BUCKET=256, SAMPLE=800, PM_ITERS=32
// R2: parallelize Gram (16 -> 512 blocks, partial+reduce).
// R3: residual & sparse attention: 64 rows x 4 reduction-chunks per block
//     (grid 256 -> 1024 each), LDS tree-combine of partials. Occupancy
//     12% -> ~50%; attacks the 1-wave/SIMD latency serialization.
// R4: identical resubmit (infra failure, no signal).
// ---------------------------------------------------------------------------

typedef unsigned int u32;

#define PRNG_MODE 0  // 0: partitionable threefry (xor out0^out1)  1: legacy split-iota

namespace {
constexpr int Bc = 2, Hc = 8, BHc = 16;
constexpr int Nc = 4096, Dc = 64, D1c = 65;
constexpr int NPROJc = 7;
constexpr int NBc = 16;      // N / BUCKET
constexpr int Sc = 800;      // SAMPLE
constexpr int PMITERc = 32;
constexpr int GCH = 128;             // Gram rows per chunk
constexpr int NCHUNK = Nc / GCH;     // 32
}

__device__ __forceinline__ u32 rotl32(u32 x, u32 d) { return (x << d) | (x >> (32u - d)); }

// Exact JAX threefry2x32 (20 rounds).
__device__ __forceinline__ void threefry2x32(u32 k0, u32 k1, u32 x0, u32 x1, u32& o0, u32& o1) {
  u32 ks2 = k0 ^ k1 ^ 0x1BD11BDAu;
  x0 += k0; x1 += k1;
#define TF_RND(r) { x0 += x1; x1 = rotl32(x1, r); x1 ^= x0; }
  TF_RND(13) TF_RND(15) TF_RND(26) TF_RND(6)
  x0 += k1; x1 += ks2 + 1u;
  TF_RND(17) TF_RND(29) TF_RND(16) TF_RND(24)
  x0 += ks2; x1 += k0 + 2u;
  TF_RND(13) TF_RND(15) TF_RND(26) TF_RND(6)
  x0 += k0; x1 += k1 + 3u;
  TF_RND(17) TF_RND(29) TF_RND(16) TF_RND(24)
  x0 += k1; x1 += ks2 + 4u;
  TF_RND(13) TF_RND(15) TF_RND(26) TF_RND(6)
  x0 += ks2; x1 += k0 + 5u;
#undef TF_RND
  o0 = x0; o1 = x1;
}

// gumbel sample for flat element i of the (800,16,4096) array, key = (0,1234)
__device__ __forceinline__ float gumbel_at(u32 i) {
  u32 o0, o1, bits;
#if PRNG_MODE == 1
  const u32 half = (u32)Sc * (u32)BHc * (u32)Nc / 2u;
  if (i < half) { threefry2x32(0u, 1234u, i, i + half, o0, o1); bits = o0; }
  else          { threefry2x32(0u, 1234u, i - half, i, o0, o1); bits = o1; }
#else
  threefry2x32(0u, 1234u, 0u, i, o0, o1);
  bits = o0 ^ o1;
#endif
  u32 fb = (bits >> 9) | 0x3f800000u;
  float u = __uint_as_float(fb) - 1.0f;           // [0,1) on 2^-23 grid
  if (u == 0.0f) u = 1.1754944e-38f;              // max(tiny, u) per jax.random.uniform
  return -logf(-logf(u));
}

// ---- K1: LSH hash codes for q and k ---------------------------------------
__global__ __launch_bounds__(256) void hash_kernel(
    const float* __restrict__ q, const float* __restrict__ k,
    const float* __restrict__ pd, int* __restrict__ hq, int* __restrict__ hk) {
  int tid = blockIdx.x * 256 + threadIdx.x;
  int which = tid / (BHc * Nc);
  int rem = tid % (BHc * Nc);
  int bh = rem / Nc, n = rem % Nc;
  int b = bh / Hc, h = bh % Hc;
  const float* x = which ? k : q;
  const float* row = x + (((size_t)b * Nc + n) * Hc + h) * Dc;   // [B,N,H,D]
  const float* pdr = pd + (size_t)bh * Dc * NPROJc;              // [B,H,D,7]
  double acc[NPROJc];
#pragma unroll
  for (int r = 0; r < NPROJc; r++) acc[r] = 0.0;
  for (int d = 0; d < Dc; d++) {
    double vv = (double)row[d];
    const float* pr = pdr + d * NPROJc;
#pragma unroll
    for (int r = 0; r < NPROJc; r++) acc[r] += vv * (double)pr[r];
  }
  int code = 0;
#pragma unroll
  for (int r = 0; r < NPROJc; r++) code |= (acc[r] > 0.0) ? (1 << r) : 0;
  int hash = code ^ (code >> 1);   // _hamming_perm == binary-reflected Gray code
  (which ? hk : hq)[bh * Nc + n] = hash;
}

// ---- K2: stable counting sort (argsort by hash) ---------------------------
__global__ __launch_bounds__(256) void sort_kernel(
    const int* __restrict__ hq, const int* __restrict__ hk,
    int* __restrict__ qidx, int* __restrict__ kidx) {
  __shared__ int sh[Nc];
  __shared__ int off[128];
  int bh = blockIdx.x;
  const int* hash = blockIdx.y ? hk : hq;
  int* out = blockIdx.y ? kidx : qidx;
  int t = threadIdx.x;
  for (int i = t; i < Nc; i += 256) sh[i] = hash[bh * Nc + i];
  __syncthreads();
  if (t < 128) {
    int c = 0;
    for (int i = 0; i < Nc; i++) c += (sh[i] == t);
    off[t] = c;
  }
  __syncthreads();
  if (t == 0) {
    int run = 0;
    for (int j = 0; j < 128; j++) { int c = off[j]; off[j] = run; run += c; }
  }
  __syncthreads();
  if (t < 128) {
    int o = off[t];
    for (int i = 0; i < Nc; i++)
      if (sh[i] == t) { out[bh * Nc + o] = i; o++; }
  }
}

// ---- K3: sorted-query block id per original query n -----------------------
__global__ __launch_bounds__(256) void qblock_kernel(
    const int* __restrict__ qidx, int* __restrict__ qblk) {
  int tid = blockIdx.x * 256 + threadIdx.x;   // [0, BH*N)
  int bh = tid / Nc, p = tid % Nc;
  int n = qidx[tid];
  qblk[bh * Nc + n] = p >> 8;                 // p / BUCKET
}

// ---- K4: block-sparse attention, 64 rows x 4 key-chunks per block ---------
__global__ __launch_bounds__(256) void sparse_kernel(
    const float* __restrict__ q, const float* __restrict__ k, const float* __restrict__ v,
    const int* __restrict__ qidx, const int* __restrict__ kidx, float* __restrict__ att) {
  __shared__ float S[8320];        // main: kb[64][64] | wb[64][64]; combine: 128*65
  float* kb = S;
  float* wb = S + 4096;
  int blk = blockIdx.x;
  int bh = blk >> 6;               // 64 blocks per bh
  int rem = blk & 63;
  int g = rem >> 2, qq = rem & 3;  // bucket, query-quadrant
  int b = bh / Hc, h = bh % Hc;
  int t = threadIdx.x;
  int r = t & 63, cid = t >> 6;
  int nq = qidx[bh * Nc + g * 256 + qq * 64 + r];
  const float* qrow = q + (((size_t)b * Nc + nq) * Hc + h) * Dc;
  float qreg[Dc];
#pragma unroll
  for (int d4 = 0; d4 < 16; d4++) {
    float4 f = ((const float4*)qrow)[d4];
    qreg[4 * d4] = f.x; qreg[4 * d4 + 1] = f.y; qreg[4 * d4 + 2] = f.z; qreg[4 * d4 + 3] = f.w;
  }
  float acc[D1c];
#pragma unroll
  for (int p = 0; p < D1c; p++) acc[p] = 0.f;
  const int* kidxB = kidx + bh * Nc + g * 256;
  for (int tile = 0; tile < 4; tile++) {
    // stage 64 keys: kb/wb rows gathered via kidx (float4)
    for (int e4 = t; e4 < 64 * 16; e4 += 256) {
      int j = e4 >> 4, d4 = e4 & 15;
      int m = kidxB[tile * 64 + j];
      const float* kr = k + (((size_t)b * Nc + m) * Hc + h) * Dc;
      const float* vr = v + (((size_t)b * Nc + m) * Hc + h) * Dc;
      ((float4*)(kb + j * 64))[d4] = ((const float4*)kr)[d4];
      ((float4*)(wb + j * 64))[d4] = ((const float4*)vr)[d4];
    }
    __syncthreads();
    for (int jj = 0; jj < 16; jj++) {
      int j = cid * 16 + jj;
      float s0 = 0, s1 = 0, s2 = 0, s3 = 0;
      const float* kj = kb + j * 64;
#pragma unroll
      for (int d = 0; d < Dc; d += 4) {
        s0 += qreg[d] * kj[d];
        s1 += qreg[d + 1] * kj[d + 1];
        s2 += qreg[d + 2] * kj[d + 2];
        s3 += qreg[d + 3] * kj[d + 3];
      }
      float e_ = expf((s0 + s1) + (s2 + s3));
      const float* wj = wb + j * 64;
#pragma unroll
      for (int p = 0; p < Dc; p++) acc[p] += e_ * wj[p];
      acc[Dc] += e_;               // v_aug's all-ones column
    }
    __syncthreads();
  }
  // tree-combine the 4 chunk partials (fixed order -> deterministic)
  if (t >= 128) { float* dst = S + (t - 128) * D1c;
#pragma unroll
    for (int p = 0; p < D1c; p++) dst[p] = acc[p]; }
  __syncthreads();
  if (t < 128) { const float* src = S + t * D1c;
#pragma unroll
    for (int p = 0; p < D1c; p++) acc[p] += src[p]; }
  __syncthreads();
  if (t >= 64 && t < 128) { float* dst = S + (t - 64) * D1c;
#pragma unroll
    for (int p = 0; p < D1c; p++) dst[p] = acc[p]; }
  __syncthreads();
  if (t < 64) {
    const float* src = S + t * D1c;
    float* arow = att + ((size_t)bh * Nc + nq) * D1c;   // scatter to original order
#pragma unroll
    for (int p = 0; p < D1c; p++) arow[p] = acc[p] + src[p];
  }
}

// ---- K5a: partial Gram over 128-row chunks (grid = BH * 32) ---------------
__global__ __launch_bounds__(256) void gram_partial_kernel(
    const float* __restrict__ v, double* __restrict__ part) {
  __shared__ float ch[GCH][D1c];
  int bh = blockIdx.x / NCHUNK, c = blockIdx.x % NCHUNK;
  int b = bh / Hc, h = bh % Hc;
  int t = threadIdx.x;
  for (int e = t; e < GCH * D1c; e += 256) {
    int r = e / D1c, p = e % D1c;
    int n = c * GCH + r;
    ch[r][p] = (p < Dc) ? v[(((size_t)b * Nc + n) * Hc + h) * Dc + p] : 1.0f;
  }
  __syncthreads();
  for (int pi = t; pi < D1c * D1c; pi += 256) {
    int tt = pi / D1c, uu = pi % D1c;
    double a = 0.0;
    for (int r = 0; r < GCH; r++) a += (double)ch[r][tt] * (double)ch[r][uu];
    part[((size_t)bh * NCHUNK + c) * (D1c * D1c) + pi] = a;
  }
}

// ---- K5b: reduce chunk partials (fixed order -> deterministic) ------------
__global__ __launch_bounds__(256) void gram_reduce_kernel(
    const double* __restrict__ part, double* __restrict__ gram) {
  int idx = blockIdx.x * 256 + threadIdx.x;   // over BH * 4225
  if (idx >= BHc * D1c * D1c) return;
  int bh = idx / (D1c * D1c), pi = idx % (D1c * D1c);
  double s = 0.0;
  for (int c = 0; c < NCHUNK; c++)
    s += part[((size_t)bh * NCHUNK + c) * (D1c * D1c) + pi];
  gram[(size_t)bh * (D1c * D1c) + pi] = s;
}

// ---- K6: power method for spectral norm -----------------------------------
__global__ __launch_bounds__(128) void power_kernel(
    const double* __restrict__ gram, const float* __restrict__ pm, double* __restrict__ sigma) {
  __shared__ double G[D1c * D1c];
  __shared__ double x[D1c], y[D1c];
  __shared__ double nrm;
  int bh = blockIdx.x, t = threadIdx.x;
  for (int e = t; e < D1c * D1c; e += 128) G[e] = gram[(size_t)bh * D1c * D1c + e];
  if (t < D1c) x[t] = (double)pm[bh * D1c + t];
  __syncthreads();
  if (t == 0) {
    double s = 0; for (int i = 0; i < D1c; i++) s += x[i] * x[i];
    nrm = sqrt(s);
  }
  __syncthreads();
  if (t < D1c) x[t] /= nrm;
  for (int it = 0; it < PMITERc; it++) {
    __syncthreads();
    if (t < D1c) {
      double s = 0;
      for (int u = 0; u < D1c; u++) s += G[t * D1c + u] * x[u];
      y[t] = s;
    }
    __syncthreads();
    if (t == 0) {
      double s = 0; for (int i = 0; i < D1c; i++) s += y[i] * y[i];
      nrm = sqrt(s);
    }
    __syncthreads();
    if (t < D1c) x[t] = y[t] / nrm;
  }
  __syncthreads();
  if (t == 0) sigma[bh] = nrm;
}

// ---- K7: sampling distribution P (sorted-key order) + log P ---------------
__global__ __launch_bounds__(256) void p_kernel(
    const float* __restrict__ v, const int* __restrict__ kidx,
    const double* __restrict__ sigma, float* __restrict__ P, float* __restrict__ logP) {
  __shared__ double buf[Nc];
  __shared__ double red[256];
  int bh = blockIdx.x, b = bh / Hc, h = bh % Hc;
  int t = threadIdx.x;
  double sg = sigma[bh];
  double part = 0.0;
  for (int n = t; n < Nc; n += 256) {
    int m = kidx[bh * Nc + n];
    const float* vr = v + (((size_t)b * Nc + m) * Hc + h) * Dc;
    double ss = 1.0;  // the appended 1.0 component of v_aug
    for (int d = 0; d < Dc; d++) { double vv = vr[d]; ss += vv * vv; }
    double Pd = sqrt(ss) / sg + (1.0 / (double)Nc);
    buf[n] = Pd;
    part += Pd;
  }
  red[t] = part;
  __syncthreads();
  for (int w = 128; w > 0; w >>= 1) {
    if (t < w) red[t] += red[t + w];
    __syncthreads();
  }
  double tot = red[0];
  for (int n = t; n < Nc; n += 256) {
    float Pf = (float)(buf[n] / tot);
    P[bh * Nc + n] = Pf;
    logP[bh * Nc + n] = logf(Pf);
  }
}

// ---- K8: categorical sampling = argmax(gumbel + logP) ---------------------
__global__ __launch_bounds__(256) void sample_kernel(
    const float* __restrict__ logP, int* __restrict__ idxs) {
  __shared__ float sv[256];
  __shared__ int si[256];
  int blk = blockIdx.x;           // bh*S + s
  int bh = blk / Sc, s = blk % Sc;
  int t = threadIdx.x;
  float best = -3.4e38f; int besti = Nc;
  const float* lp = logP + bh * Nc;
  u32 base = ((u32)(s * BHc + bh)) * (u32)Nc;  // flat index into (800,16,4096)
  for (int n = t; n < Nc; n += 256) {
    float val = gumbel_at(base + (u32)n) + lp[n];
    if (val > best || (val == best && n < besti)) { best = val; besti = n; }
  }
  sv[t] = best; si[t] = besti;
  __syncthreads();
  for (int w = 128; w > 0; w >>= 1) {
    if (t < w) {
      float v2 = sv[t + w]; int i2 = si[t + w];
      if (v2 > sv[t] || (v2 == sv[t] && i2 < si[t])) { sv[t] = v2; si[t] = i2; }
    }
    __syncthreads();
  }
  if (t == 0) idxs[blk] = si[0];
}

// ---- K9: gather sampled K rows, sig*V_aug rows, sample block ids ----------
__global__ __launch_bounds__(128) void gather_kernel(
    const float* __restrict__ key, const float* __restrict__ value,
    const int* __restrict__ kidx, const float* __restrict__ P, const int* __restrict__ idxs,
    float* __restrict__ Kpi, float* __restrict__ sigV, int* __restrict__ sblk) {
  int blk = blockIdx.x;           // bh*S + s
  int bh = blk / Sc;
  int b = bh / Hc, h = bh % Hc;
  int t = threadIdx.x;
  int m = idxs[blk];
  int src = kidx[bh * Nc + m];
  float Pv = P[bh * Nc + m];
  float sg = 1.0f / (Pv * (float)Sc);
  const float* kr = key + (((size_t)b * Nc + src) * Hc + h) * Dc;
  const float* vr = value + (((size_t)b * Nc + src) * Hc + h) * Dc;
  if (t < Dc) Kpi[(size_t)blk * Dc + t] = kr[t];
  if (t < D1c) sigV[(size_t)blk * D1c + t] = sg * ((t < Dc) ? vr[t] : 1.0f);
  if (t == 0) sblk[blk] = m >> 8;
}

// ---- K10: residual attention, 64 rows x 4 sample-chunks per block ---------
__global__ __launch_bounds__(256) void residual_kernel(
    const float* __restrict__ q,
    const float* __restrict__ Kpi, const float* __restrict__ sigV, const int* __restrict__ sblk,
    const int* __restrict__ qblk, const float* __restrict__ att, float* __restrict__ out) {
  __shared__ float S[8320];        // main: kl[64][64] | wl[64*65]; combine: 128*65
  __shared__ int bl[64];
  float* kl = S;
  float* wl = S + 4096;
  int blk = blockIdx.x;
  int bh = blk >> 6;               // 64 row-groups per bh
  int n0 = (blk & 63) * 64;
  int b = bh / Hc, h = bh % Hc;
  int t = threadIdx.x;
  int r = t & 63, cid = t >> 6;
  int n = n0 + r;
  const float* qrow = q + (((size_t)b * Nc + n) * Hc + h) * Dc;
  float qreg[Dc];
#pragma unroll
  for (int d4 = 0; d4 < 16; d4++) {
    float4 f = ((const float4*)qrow)[d4];
    qreg[4 * d4] = f.x; qreg[4 * d4 + 1] = f.y; qreg[4 * d4 + 2] = f.z; qreg[4 * d4 + 3] = f.w;
  }
  int myblk = qblk[bh * Nc + n];
  float acc[D1c];
#pragma unroll
  for (int p = 0; p < D1c; p++) acc[p] = 0.f;
  const float* KpiB = Kpi + (size_t)bh * Sc * Dc;
  const float* sigVB = sigV + (size_t)bh * Sc * D1c;
  const int* sblkB = sblk + bh * Sc;
  for (int tile = 0; tile < 13; tile++) {       // 12 tiles of 64 + tail 32
    int base = tile * 64;
    int cnt = (tile < 12) ? 64 : 32;
    for (int e4 = t; e4 < cnt * 16; e4 += 256) {   // kl: cnt x 64 (float4)
      int j = e4 >> 4, d4 = e4 & 15;
      ((float4*)(kl + j * 64))[d4] = ((const float4*)(KpiB + (base + j) * 64))[d4];
    }
    for (int e4 = t; e4 < cnt * 65 / 4; e4 += 256) // wl: cnt x 65 flat (65*64 % 4 == 0)
      ((float4*)wl)[e4] = ((const float4*)(sigVB + base * 65))[e4];
    if (t < cnt) bl[t] = sblkB[base + t];
    __syncthreads();
    int per = cnt >> 2;
    for (int jj = 0; jj < per; jj++) {
      int j = cid * per + jj;
      float s0 = 0, s1 = 0, s2 = 0, s3 = 0;
      const float* kj = kl + j * 64;
#pragma unroll
      for (int d = 0; d < Dc; d += 4) {
        s0 += qreg[d] * kj[d];
        s1 += qreg[d + 1] * kj[d + 1];
        s2 += qreg[d + 2] * kj[d + 2];
        s3 += qreg[d + 3] * kj[d + 3];
      }
      float e_ = expf((s0 + s1) + (s2 + s3));
      float w = (bl[j] == myblk) ? 0.0f : e_;    // mask: sample in query's own block
      const float* wj = wl + j * 65;
#pragma unroll
      for (int p = 0; p < D1c; p++) acc[p] += w * wj[p];
    }
    __syncthreads();
  }
  // tree-combine the 4 chunk partials (fixed order -> deterministic)
  if (t >= 128) { float* dst = S + (t - 128) * D1c;
#pragma unroll
    for (int p = 0; p < D1c; p++) dst[p] = acc[p]; }
  __syncthreads();
  if (t < 128) { const float* src = S + t * D1c;
#pragma unroll
    for (int p = 0; p < D1c; p++) acc[p] += src[p]; }
  __syncthreads();
  if (t >= 64 && t < 128) { float* dst = S + (t - 64) * D1c;
#pragma unroll
    for (int p = 0; p < D1c; p++) dst[p] = acc[p]; }
  __syncthreads();
  if (t < 64) {
    const float* src = S + t * D1c;
#pragma unroll
    for (int p = 0; p < D1c; p++) acc[p] += src[p];
    const float* arow = att + ((size_t)bh * Nc + n) * D1c;
    float denom = arow[Dc] + acc[Dc];
    float* orow = out + ((size_t)bh * Nc + n) * Dc;
#pragma unroll
    for (int d = 0; d < Dc; d++) orow[d] = (arow[d] + acc[d]) / denom;
  }
}

// ---------------------------------------------------------------------------
extern "C" void kernel_launch(void* const* d_in, const int* in_sizes, int n_in,
                              void* d_out, int out_size, void* d_ws, size_t ws_size,
                              hipStream_t stream) {
  const float* q  = (const float*)d_in[0];
  const float* k  = (const float*)d_in[1];
  const float* v  = (const float*)d_in[2];
  const float* pd = (const float*)d_in[3];
  const float* pm = (const float*)d_in[4];
  float* out = (float*)d_out;

  char* w = (char*)d_ws;
  size_t off = 0;
  auto take = [&](size_t nbytes) -> void* {
    void* p = w + off;
    off += (nbytes + 255) & ~(size_t)255;
    return p;
  };
  double* gram = (double*)take((size_t)BHc * D1c * D1c * sizeof(double));
  double* sigm = (double*)take((size_t)BHc * sizeof(double));
  int* hq   = (int*)take((size_t)BHc * Nc * 4);
  int* hk   = (int*)take((size_t)BHc * Nc * 4);
  int* qidx = (int*)take((size_t)BHc * Nc * 4);
  int* kidx = (int*)take((size_t)BHc * Nc * 4);
  int* qblk = (int*)take((size_t)BHc * Nc * 4);
  float* P    = (float*)take((size_t)BHc * Nc * 4);
  float* logP = (float*)take((size_t)BHc * Nc * 4);
  int* idxs = (int*)take((size_t)BHc * Sc * 4);
  int* sblk = (int*)take((size_t)BHc * Sc * 4);
  float* Kpi  = (float*)take((size_t)BHc * Sc * Dc * 4);
  float* sigV = (float*)take((size_t)BHc * Sc * D1c * 4);
  // union region: Gram chunk partials (used first), then att (written after
  // gram_reduce has consumed the partials — stream order guarantees this).
  size_t partBytes = (size_t)BHc * NCHUNK * D1c * D1c * sizeof(double);
  size_t attBytes  = (size_t)BHc * Nc * D1c * 4;
  void* uni = take(partBytes > attBytes ? partBytes : attBytes);
  double* part = (double*)uni;
  float*  att  = (float*)uni;
  (void)ws_size; (void)in_sizes; (void)n_in; (void)out_size;

  hash_kernel<<<2 * BHc * Nc / 256, 256, 0, stream>>>(q, k, pd, hq, hk);
  sort_kernel<<<dim3(BHc, 2), 256, 0, stream>>>(hq, hk, qidx, kidx);
  qblock_kernel<<<BHc * Nc / 256, 256, 0, stream>>>(qidx, qblk);
  gram_partial_kernel<<<BHc * NCHUNK, 256, 0, stream>>>(v, part);
  gram_reduce_kernel<<<(BHc * D1c * D1c + 255) / 256, 256, 0, stream>>>(part, gram);
  power_kernel<<<BHc, 128, 0, stream>>>(gram, pm, sigm);
  p_kernel<<<BHc, 256, 0, stream>>>(v, kidx, sigm, P, logP);
  sample_kernel<<<BHc * Sc, 256, 0, stream>>>(logP, idxs);
  gather_kernel<<<BHc * Sc, 128, 0, stream>>>(k, v, kidx, P, idxs, Kpi, sigV, sblk);
  sparse_kernel<<<BHc * NBc * 4, 256, 0, stream>>>(q, k, v, qidx, kidx, att);  // writes att (over part)
  residual_kernel<<<BHc * 64, 256, 0, stream>>>(q, Kpi, sigV, sblk, qblk, att, out);
}

// Round 6
// 1024.132 us; speedup vs baseline: 7.6903x; 1.1869x over previous
//
#include <hip/hip_runtime.h>
#include <stdint.h>
#include <math.h>

// ---------------------------------------------------------------------------
// CosineHammingAttention — bit-faithful HIP port of the JAX reference.
// B=2 H=8 N=4096 D=64, NUM_PROJS=7, BUCKET=256, SAMPLE=800, PM_ITERS=32
// R2: parallelize Gram (partial+reduce).  R3: 64 rows x 4 chunks attention.
// R5: float4 LDS reads + __expf in attention; sigV stride 68; p_kernel split
//     128+256 blocks; sort 512-thr quarter-split (fuses qblock); sample fuses
//     gather + __logf gumbel; gram f32 chunk accum.
// ---------------------------------------------------------------------------

typedef unsigned int u32;

namespace {
constexpr int Bc = 2, Hc = 8, BHc = 16;
constexpr int Nc = 4096, Dc = 64, D1c = 65;
constexpr int NBc = 16;      // N / BUCKET
constexpr int Sc = 800;      // SAMPLE
constexpr int PMITERc = 32;
constexpr int GCH = 128;             // Gram rows per chunk
constexpr int NCHUNK = Nc / GCH;     // 32
constexpr int WST = 68;              // padded sigV row stride (16B-aligned rows)
}

__device__ __forceinline__ u32 rotl32(u32 x, u32 d) { return (x << d) | (x >> (32u - d)); }

// Exact JAX threefry2x32 (20 rounds).
__device__ __forceinline__ void threefry2x32(u32 k0, u32 k1, u32 x0, u32 x1, u32& o0, u32& o1) {
  u32 ks2 = k0 ^ k1 ^ 0x1BD11BDAu;
  x0 += k0; x1 += k1;
#define TF_RND(r) { x0 += x1; x1 = rotl32(x1, r); x1 ^= x0; }
  TF_RND(13) TF_RND(15) TF_RND(26) TF_RND(6)
  x0 += k1; x1 += ks2 + 1u;
  TF_RND(17) TF_RND(29) TF_RND(16) TF_RND(24)
  x0 += ks2; x1 += k0 + 2u;
  TF_RND(13) TF_RND(15) TF_RND(26) TF_RND(6)
  x0 += k0; x1 += k1 + 3u;
  TF_RND(17) TF_RND(29) TF_RND(16) TF_RND(24)
  x0 += k1; x1 += ks2 + 4u;
  TF_RND(13) TF_RND(15) TF_RND(26) TF_RND(6)
  x0 += ks2; x1 += k0 + 5u;
#undef TF_RND
  o0 = x0; o1 = x1;
}

// gumbel sample for flat element i of the (800,16,4096) array, key = (0,1234)
// partitionable threefry: bits = out0 ^ out1 of counter (0, i)
__device__ __forceinline__ float gumbel_at(u32 i) {
  u32 o0, o1;
  threefry2x32(0u, 1234u, 0u, i, o0, o1);
  u32 bits = o0 ^ o1;
  u32 fb = (bits >> 9) | 0x3f800000u;
  float u = __uint_as_float(fb) - 1.0f;           // [0,1) on 2^-23 grid
  if (u == 0.0f) u = 1.1754944e-38f;              // max(tiny, u) per jax.random.uniform
  return -__logf(-__logf(u));
}

// ---- K1: LSH hash codes for q and k ---------------------------------------
__global__ __launch_bounds__(256) void hash_kernel(
    const float* __restrict__ q, const float* __restrict__ k,
    const float* __restrict__ pd, int* __restrict__ hq, int* __restrict__ hk) {
  int tid = blockIdx.x * 256 + threadIdx.x;
  int which = tid / (BHc * Nc);
  int rem = tid % (BHc * Nc);
  int bh = rem / Nc, n = rem % Nc;
  int b = bh / Hc, h = bh % Hc;
  const float* x = which ? k : q;
  const float* row = x + (((size_t)b * Nc + n) * Hc + h) * Dc;   // [B,N,H,D]
  const float* pdr = pd + (size_t)bh * Dc * 7;                   // [B,H,D,7]
  double acc[7];
#pragma unroll
  for (int r = 0; r < 7; r++) acc[r] = 0.0;
  for (int d = 0; d < Dc; d++) {
    double vv = (double)row[d];
    const float* pr = pdr + d * 7;
#pragma unroll
    for (int r = 0; r < 7; r++) acc[r] += vv * (double)pr[r];
  }
  int code = 0;
#pragma unroll
  for (int r = 0; r < 7; r++) code |= (acc[r] > 0.0) ? (1 << r) : 0;
  int hash = code ^ (code >> 1);   // _hamming_perm == binary-reflected Gray code
  (which ? hk : hq)[bh * Nc + n] = hash;
}

// ---- K2: stable counting sort, quarter-split; q-branch also writes qblk ---
__global__ __launch_bounds__(512) void sort_kernel(
    const int* __restrict__ hq, const int* __restrict__ hk,
    int* __restrict__ qidx, int* __restrict__ kidx, int* __restrict__ qblk) {
  __shared__ int sh[Nc];
  __shared__ int cnt[4][128];
  __shared__ int off[128];
  int bh = blockIdx.x;
  int which = blockIdx.y;
  const int* hash = which ? hk : hq;
  int* out = which ? kidx : qidx;
  int t = threadIdx.x;
  for (int i = t; i < Nc; i += 512) sh[i] = hash[bh * Nc + i];
  __syncthreads();
  int qr = t >> 7, b = t & 127;      // quarter, bin
  int c = 0;
  for (int i = qr * 1024; i < (qr + 1) * 1024; i++) c += (sh[i] == b);
  cnt[qr][b] = c;
  __syncthreads();
  if (t == 0) {
    int run = 0;
    for (int j = 0; j < 128; j++) {
      int tot = cnt[0][j] + cnt[1][j] + cnt[2][j] + cnt[3][j];
      off[j] = run; run += tot;
    }
  }
  __syncthreads();
  int o = off[b];
  for (int qq = 0; qq < qr; qq++) o += cnt[qq][b];
  for (int i = qr * 1024; i < (qr + 1) * 1024; i++)
    if (sh[i] == b) {
      out[bh * Nc + o] = i;
      if (which == 0) qblk[bh * Nc + i] = o >> 8;
      o++;
    }
}

// ---- K4: block-sparse attention, 64 rows x 4 key-chunks per block ---------
__global__ __launch_bounds__(256) void sparse_kernel(
    const float* __restrict__ q, const float* __restrict__ k, const float* __restrict__ v,
    const int* __restrict__ qidx, const int* __restrict__ kidx, float* __restrict__ att) {
  __shared__ float S[8320];        // main: kb[64][64] | wb[64][64]; combine: 128*65
  float* kb = S;
  float* wb = S + 4096;
  int blk = blockIdx.x;
  int bh = blk >> 6;               // 64 blocks per bh
  int rem = blk & 63;
  int g = rem >> 2, qq = rem & 3;  // bucket, query-quadrant
  int b = bh / Hc, h = bh % Hc;
  int t = threadIdx.x;
  int r = t & 63, cid = t >> 6;
  int nq = qidx[bh * Nc + g * 256 + qq * 64 + r];
  const float* qrow = q + (((size_t)b * Nc + nq) * Hc + h) * Dc;
  float qreg[Dc];
#pragma unroll
  for (int d4 = 0; d4 < 16; d4++) {
    float4 f = ((const float4*)qrow)[d4];
    qreg[4 * d4] = f.x; qreg[4 * d4 + 1] = f.y; qreg[4 * d4 + 2] = f.z; qreg[4 * d4 + 3] = f.w;
  }
  float acc[Dc];
  float accS = 0.f;
#pragma unroll
  for (int p = 0; p < Dc; p++) acc[p] = 0.f;
  const int* kidxB = kidx + bh * Nc + g * 256;
  for (int tile = 0; tile < 4; tile++) {
    for (int e4 = t; e4 < 64 * 16; e4 += 256) {
      int j = e4 >> 4, d4 = e4 & 15;
      int m = kidxB[tile * 64 + j];
      const float* kr = k + (((size_t)b * Nc + m) * Hc + h) * Dc;
      const float* vr = v + (((size_t)b * Nc + m) * Hc + h) * Dc;
      ((float4*)(kb + j * 64))[d4] = ((const float4*)kr)[d4];
      ((float4*)(wb + j * 64))[d4] = ((const float4*)vr)[d4];
    }
    __syncthreads();
    for (int jj = 0; jj < 16; jj++) {
      int j = cid * 16 + jj;
      float s0 = 0, s1 = 0, s2 = 0, s3 = 0;
      const float4* kj4 = (const float4*)(kb + j * 64);
#pragma unroll
      for (int d4 = 0; d4 < 16; d4++) {
        float4 kv = kj4[d4];
        s0 += qreg[4 * d4]     * kv.x;
        s1 += qreg[4 * d4 + 1] * kv.y;
        s2 += qreg[4 * d4 + 2] * kv.z;
        s3 += qreg[4 * d4 + 3] * kv.w;
      }
      float e_ = __expf((s0 + s1) + (s2 + s3));
      const float4* wj4 = (const float4*)(wb + j * 64);
#pragma unroll
      for (int p4 = 0; p4 < 16; p4++) {
        float4 wv = wj4[p4];
        acc[4 * p4]     += e_ * wv.x;
        acc[4 * p4 + 1] += e_ * wv.y;
        acc[4 * p4 + 2] += e_ * wv.z;
        acc[4 * p4 + 3] += e_ * wv.w;
      }
      accS += e_;                  // v_aug's all-ones column
    }
    __syncthreads();
  }
  // tree-combine the 4 chunk partials (fixed order -> deterministic)
  if (t >= 128) { float* dst = S + (t - 128) * D1c;
#pragma unroll
    for (int p = 0; p < Dc; p++) dst[p] = acc[p];
    dst[Dc] = accS; }
  __syncthreads();
  if (t < 128) { const float* src = S + t * D1c;
#pragma unroll
    for (int p = 0; p < Dc; p++) acc[p] += src[p];
    accS += src[Dc]; }
  __syncthreads();
  if (t >= 64 && t < 128) { float* dst = S + (t - 64) * D1c;
#pragma unroll
    for (int p = 0; p < Dc; p++) dst[p] = acc[p];
    dst[Dc] = accS; }
  __syncthreads();
  if (t < 64) {
    const float* src = S + t * D1c;
    float* arow = att + ((size_t)bh * Nc + nq) * D1c;   // scatter to original order
#pragma unroll
    for (int p = 0; p < Dc; p++) arow[p] = acc[p] + src[p];
    arow[Dc] = accS + src[Dc];
  }
}

// ---- K5a: partial Gram over 128-row chunks (f32 accum, grid = BH*32) ------
__global__ __launch_bounds__(256) void gram_partial_kernel(
    const float* __restrict__ v, double* __restrict__ part) {
  __shared__ float ch[GCH][D1c];
  int bh = blockIdx.x / NCHUNK, c = blockIdx.x % NCHUNK;
  int b = bh / Hc, h = bh % Hc;
  int t = threadIdx.x;
  for (int e = t; e < GCH * D1c; e += 256) {
    int r = e / D1c, p = e % D1c;
    int n = c * GCH + r;
    ch[r][p] = (p < Dc) ? v[(((size_t)b * Nc + n) * Hc + h) * Dc + p] : 1.0f;
  }
  __syncthreads();
  for (int pi = t; pi < D1c * D1c; pi += 256) {
    int tt = pi / D1c, uu = pi % D1c;
    float a = 0.0f;
    for (int r = 0; r < GCH; r++) a += ch[r][tt] * ch[r][uu];
    part[((size_t)bh * NCHUNK + c) * (D1c * D1c) + pi] = (double)a;
  }
}

// ---- K5b: reduce chunk partials (fixed order -> deterministic) ------------
__global__ __launch_bounds__(256) void gram_reduce_kernel(
    const double* __restrict__ part, double* __restrict__ gram) {
  int idx = blockIdx.x * 256 + threadIdx.x;   // over BH * 4225
  if (idx >= BHc * D1c * D1c) return;
  int bh = idx / (D1c * D1c), pi = idx % (D1c * D1c);
  double s = 0.0;
  for (int c = 0; c < NCHUNK; c++)
    s += part[((size_t)bh * NCHUNK + c) * (D1c * D1c) + pi];
  gram[(size_t)bh * (D1c * D1c) + pi] = s;
}

// ---- K6: power method for spectral norm -----------------------------------
__global__ __launch_bounds__(128) void power_kernel(
    const double* __restrict__ gram, const float* __restrict__ pm, double* __restrict__ sigma) {
  __shared__ double G[D1c * D1c];
  __shared__ double x[D1c], y[D1c];
  __shared__ double nrm;
  int bh = blockIdx.x, t = threadIdx.x;
  for (int e = t; e < D1c * D1c; e += 128) G[e] = gram[(size_t)bh * D1c * D1c + e];
  if (t < D1c) x[t] = (double)pm[bh * D1c + t];
  __syncthreads();
  if (t == 0) {
    double s = 0; for (int i = 0; i < D1c; i++) s += x[i] * x[i];
    nrm = sqrt(s);
  }
  __syncthreads();
  if (t < D1c) x[t] /= nrm;
  for (int it = 0; it < PMITERc; it++) {
    __syncthreads();
    if (t < D1c) {
      double s = 0;
      for (int u = 0; u < D1c; u++) s += G[t * D1c + u] * x[u];
      y[t] = s;
    }
    __syncthreads();
    if (t == 0) {
      double s = 0; for (int i = 0; i < D1c; i++) s += y[i] * y[i];
      nrm = sqrt(s);
    }
    __syncthreads();
    if (t < D1c) x[t] = y[t] / nrm;
  }
  __syncthreads();
  if (t == 0) sigma[bh] = nrm;
}

// ---- K7a: unnormalized P + per-segment partial sums (grid = BH*8) ---------
__global__ __launch_bounds__(256) void p_partial_kernel(
    const float* __restrict__ v, const int* __restrict__ kidx,
    const double* __restrict__ sigma, double* __restrict__ Pun, double* __restrict__ psum) {
  __shared__ double red[256];
  int blk = blockIdx.x;
  int bh = blk >> 3, seg = blk & 7;
  int b = bh / Hc, h = bh % Hc;
  int t = threadIdx.x;
  double sg = sigma[bh];
  double part = 0.0;
  for (int n = seg * 512 + t; n < (seg + 1) * 512; n += 256) {
    int m = kidx[bh * Nc + n];
    const float* vr = v + (((size_t)b * Nc + m) * Hc + h) * Dc;
    double ss = 1.0;  // the appended 1.0 component of v_aug
    for (int d = 0; d < Dc; d++) { double vv = vr[d]; ss += vv * vv; }
    double Pd = sqrt(ss) / sg + (1.0 / (double)Nc);
    Pun[bh * Nc + n] = Pd;
    part += Pd;
  }
  red[t] = part;
  __syncthreads();
  for (int w = 128; w > 0; w >>= 1) {
    if (t < w) red[t] += red[t + w];
    __syncthreads();
  }
  if (t == 0) psum[blk] = red[0];
}

// ---- K7b: normalize + log -------------------------------------------------
__global__ __launch_bounds__(256) void p_final_kernel(
    const double* __restrict__ Pun, const double* __restrict__ psum,
    float* __restrict__ P, float* __restrict__ logP) {
  int idx = blockIdx.x * 256 + threadIdx.x;   // over BH*N
  int bh = idx / Nc;
  double tot = 0.0;
#pragma unroll
  for (int s = 0; s < 8; s++) tot += psum[bh * 8 + s];
  float Pf = (float)(Pun[idx] / tot);
  P[idx] = Pf;
  logP[idx] = logf(Pf);
}

// ---- K8: categorical sampling (argmax gumbel+logP) + fused gather ---------
__global__ __launch_bounds__(256) void sample_kernel(
    const float* __restrict__ logP, const int* __restrict__ kidx,
    const float* __restrict__ P, const float* __restrict__ key, const float* __restrict__ value,
    float* __restrict__ Kpi, float* __restrict__ sigV, int* __restrict__ sblk) {
  __shared__ float sv[256];
  __shared__ int si[256];
  int blk = blockIdx.x;           // bh*S + s
  int bh = blk / Sc, s = blk % Sc;
  int b = bh / Hc, h = bh % Hc;
  int t = threadIdx.x;
  float best = -3.4e38f; int besti = Nc;
  const float* lp = logP + bh * Nc;
  u32 base = ((u32)(s * BHc + bh)) * (u32)Nc;  // flat index into (800,16,4096)
  for (int n = t; n < Nc; n += 256) {
    float val = gumbel_at(base + (u32)n) + lp[n];
    if (val > best || (val == best && n < besti)) { best = val; besti = n; }
  }
  sv[t] = best; si[t] = besti;
  __syncthreads();
  for (int w = 128; w > 0; w >>= 1) {
    if (t < w) {
      float v2 = sv[t + w]; int i2 = si[t + w];
      if (v2 > sv[t] || (v2 == sv[t] && i2 < si[t])) { sv[t] = v2; si[t] = i2; }
    }
    __syncthreads();
  }
  int m = si[0];
  if (t == 0) sblk[blk] = m >> 8;
  int src = kidx[bh * Nc + m];
  float sg = 1.0f / (P[bh * Nc + m] * (float)Sc);
  const float* kr = key + (((size_t)b * Nc + src) * Hc + h) * Dc;
  const float* vr = value + (((size_t)b * Nc + src) * Hc + h) * Dc;
  if (t < Dc) Kpi[(size_t)blk * Dc + t] = kr[t];
  if (t < WST) sigV[(size_t)blk * WST + t] =
      (t < Dc) ? sg * vr[t] : ((t == Dc) ? sg : 0.0f);   // [65..67] = pad
}

// ---- K10: residual attention, 64 rows x 4 sample-chunks per block ---------
__global__ __launch_bounds__(256) void residual_kernel(
    const float* __restrict__ q,
    const float* __restrict__ Kpi, const float* __restrict__ sigV, const int* __restrict__ sblk,
    const int* __restrict__ qblk, const float* __restrict__ att, float* __restrict__ out) {
  __shared__ float S[8448];        // main: kl[64][64] | wl[64][68]; combine: 128*65
  __shared__ int bl[64];
  float* kl = S;
  float* wl = S + 4096;
  int blk = blockIdx.x;
  int bh = blk >> 6;               // 64 row-groups per bh
  int n0 = (blk & 63) * 64;
  int b = bh / Hc, h = bh % Hc;
  int t = threadIdx.x;
  int r = t & 63, cid = t >> 6;
  int n = n0 + r;
  const float* qrow = q + (((size_t)b * Nc + n) * Hc + h) * Dc;
  float qreg[Dc];
#pragma unroll
  for (int d4 = 0; d4 < 16; d4++) {
    float4 f = ((const float4*)qrow)[d4];
    qreg[4 * d4] = f.x; qreg[4 * d4 + 1] = f.y; qreg[4 * d4 + 2] = f.z; qreg[4 * d4 + 3] = f.w;
  }
  int myblk = qblk[bh * Nc + n];
  float acc[WST];
#pragma unroll
  for (int p = 0; p < WST; p++) acc[p] = 0.f;
  const float* KpiB = Kpi + (size_t)bh * Sc * Dc;
  const float* sigVB = sigV + (size_t)bh * Sc * WST;
  const int* sblkB = sblk + bh * Sc;
  for (int tile = 0; tile < 13; tile++) {       // 12 tiles of 64 + tail 32
    int base = tile * 64;
    int cnt = (tile < 12) ? 64 : 32;
    for (int e4 = t; e4 < cnt * 16; e4 += 256)     // kl: flat float4 copy
      ((float4*)kl)[e4] = ((const float4*)(KpiB + (size_t)base * Dc))[e4];
    for (int e4 = t; e4 < cnt * 17; e4 += 256)     // wl: flat float4 copy (stride 68)
      ((float4*)wl)[e4] = ((const float4*)(sigVB + (size_t)base * WST))[e4];
    if (t < cnt) bl[t] = sblkB[base + t];
    __syncthreads();
    int per = cnt >> 2;
    for (int jj = 0; jj < per; jj++) {
      int j = cid * per + jj;
      float s0 = 0, s1 = 0, s2 = 0, s3 = 0;
      const float4* kj4 = (const float4*)(kl + j * 64);
#pragma unroll
      for (int d4 = 0; d4 < 16; d4++) {
        float4 kv = kj4[d4];
        s0 += qreg[4 * d4]     * kv.x;
        s1 += qreg[4 * d4 + 1] * kv.y;
        s2 += qreg[4 * d4 + 2] * kv.z;
        s3 += qreg[4 * d4 + 3] * kv.w;
      }
      float e_ = __expf((s0 + s1) + (s2 + s3));
      float w = (bl[j] == myblk) ? 0.0f : e_;    // mask: sample in query's own block
      const float4* wj4 = (const float4*)(wl + j * WST);
#pragma unroll
      for (int p4 = 0; p4 < 17; p4++) {
        float4 wv = wj4[p4];
        acc[4 * p4]     += w * wv.x;
        acc[4 * p4 + 1] += w * wv.y;
        acc[4 * p4 + 2] += w * wv.z;
        acc[4 * p4 + 3] += w * wv.w;
      }
    }
    __syncthreads();
  }
  // tree-combine the 4 chunk partials (fixed order -> deterministic)
  if (t >= 128) { float* dst = S + (t - 128) * D1c;
#pragma unroll
    for (int p = 0; p < D1c; p++) dst[p] = acc[p]; }
  __syncthreads();
  if (t < 128) { const float* src = S + t * D1c;
#pragma unroll
    for (int p = 0; p < D1c; p++) acc[p] += src[p]; }
  __syncthreads();
  if (t >= 64 && t < 128) { float* dst = S + (t - 64) * D1c;
#pragma unroll
    for (int p = 0; p < D1c; p++) dst[p] = acc[p]; }
  __syncthreads();
  if (t < 64) {
    const float* src = S + t * D1c;
#pragma unroll
    for (int p = 0; p < D1c; p++) acc[p] += src[p];
    const float* arow = att + ((size_t)bh * Nc + n) * D1c;
    float denom = arow[Dc] + acc[Dc];
    float* orow = out + ((size_t)bh * Nc + n) * Dc;
#pragma unroll
    for (int d = 0; d < Dc; d++) orow[d] = (arow[d] + acc[d]) / denom;
  }
}

// ---------------------------------------------------------------------------
extern "C" void kernel_launch(void* const* d_in, const int* in_sizes, int n_in,
                              void* d_out, int out_size, void* d_ws, size_t ws_size,
                              hipStream_t stream) {
  const float* q  = (const float*)d_in[0];
  const float* k  = (const float*)d_in[1];
  const float* v  = (const float*)d_in[2];
  const float* pd = (const float*)d_in[3];
  const float* pm = (const float*)d_in[4];
  float* out = (float*)d_out;

  char* w = (char*)d_ws;
  size_t off = 0;
  auto take = [&](size_t nbytes) -> void* {
    void* p = w + off;
    off += (nbytes + 255) & ~(size_t)255;
    return p;
  };
  double* gram = (double*)take((size_t)BHc * D1c * D1c * sizeof(double));
  double* sigm = (double*)take((size_t)BHc * sizeof(double));
  double* Pun  = (double*)take((size_t)BHc * Nc * sizeof(double));
  double* psum = (double*)take((size_t)BHc * 8 * sizeof(double));
  int* hq   = (int*)take((size_t)BHc * Nc * 4);
  int* hk   = (int*)take((size_t)BHc * Nc * 4);
  int* qidx = (int*)take((size_t)BHc * Nc * 4);
  int* kidx = (int*)take((size_t)BHc * Nc * 4);
  int* qblk = (int*)take((size_t)BHc * Nc * 4);
  float* P    = (float*)take((size_t)BHc * Nc * 4);
  float* logP = (float*)take((size_t)BHc * Nc * 4);
  int* sblk = (int*)take((size_t)BHc * Sc * 4);
  float* Kpi  = (float*)take((size_t)BHc * Sc * Dc * 4);
  float* sigV = (float*)take((size_t)BHc * Sc * WST * 4);
  // union region: Gram chunk partials (used first), then att (written after
  // gram_reduce has consumed the partials — stream order guarantees this).
  size_t partBytes = (size_t)BHc * NCHUNK * D1c * D1c * sizeof(double);
  size_t attBytes  = (size_t)BHc * Nc * D1c * 4;
  void* uni = take(partBytes > attBytes ? partBytes : attBytes);
  double* part = (double*)uni;
  float*  att  = (float*)uni;
  (void)ws_size; (void)in_sizes; (void)n_in; (void)out_size;

  hash_kernel<<<2 * BHc * Nc / 256, 256, 0, stream>>>(q, k, pd, hq, hk);
  sort_kernel<<<dim3(BHc, 2), 512, 0, stream>>>(hq, hk, qidx, kidx, qblk);
  gram_partial_kernel<<<BHc * NCHUNK, 256, 0, stream>>>(v, part);
  gram_reduce_kernel<<<(BHc * D1c * D1c + 255) / 256, 256, 0, stream>>>(part, gram);
  power_kernel<<<BHc, 128, 0, stream>>>(gram, pm, sigm);
  p_partial_kernel<<<BHc * 8, 256, 0, stream>>>(v, kidx, sigm, Pun, psum);
  p_final_kernel<<<BHc * Nc / 256, 256, 0, stream>>>(Pun, psum, P, logP);
  sample_kernel<<<BHc * Sc, 256, 0, stream>>>(logP, kidx, P, k, v, Kpi, sigV, sblk);
  sparse_kernel<<<BHc * NBc * 4, 256, 0, stream>>>(q, k, v, qidx, kidx, att);  // writes att (over part)
  residual_kernel<<<BHc * 64, 256, 0, stream>>>(q, Kpi, sigV, sblk, qblk, att, out);
}